// Round 2
// baseline (682.619 us; speedup 1.0000x reference)
//
#include <hip/hip_runtime.h>
#include <hip/hip_bf16.h>

// Problem constants
#define NN 50000      // nodes
#define NE 800000     // edges
#define FD 4          // features
#define TD 12         // timesteps
#define CD 32         // channels
#define HD 12         // horizon
#define FT 48         // FD*TD

// Workspace layout (float offsets)
#define OFF_DEG   0
#define OFF_DIS   (NN)
#define OFF_NORM  (2*NN)
#define OFF_Y     (2*NN + NE)
#define OFF_CST   (2*NN + NE + NN*FT)
// cst block: Az[128] @0, cz[32] @128, Ah[128] @160, ch[32] @288, probs[12] @320

__global__ void zero_deg_kernel(float* __restrict__ deg) {
    int i = blockIdx.x * blockDim.x + threadIdx.x;
    if (i < NN) deg[i] = 0.f;
}

// ---------------------------------------------------------------------------
// Precompute fused small matrices:
//   Az = Wz @ Wlz[0:32,:]   (4x32)      cz = blz + bz @ Wlz[0:32,:]
//   Ah = Wh @ Wlh[0:32,:]   (4x32)      ch = blh + bh @ Wlh[0:32,:]
//   probs = softmax(attention)
// (H0 stays zero in the reference, so R / Wr / bottom halves of Wl* are dead.)
// ---------------------------------------------------------------------------
__global__ void precompute_kernel(const float* __restrict__ Wz, const float* __restrict__ bz,
                                  const float* __restrict__ Wlz, const float* __restrict__ blz,
                                  const float* __restrict__ Wh, const float* __restrict__ bh,
                                  const float* __restrict__ Wlh, const float* __restrict__ blh,
                                  const float* __restrict__ attention,
                                  float* __restrict__ cst) {
    int tid = threadIdx.x;
    if (tid < 128) {
        int f = tid >> 5, c = tid & 31;
        float s = 0.f, s2 = 0.f;
        #pragma unroll
        for (int k = 0; k < 32; ++k) {
            s  += Wz[f*32 + k] * Wlz[k*32 + c];
            s2 += Wh[f*32 + k] * Wlh[k*32 + c];
        }
        cst[tid]       = s;   // Az[f][c]
        cst[160 + tid] = s2;  // Ah[f][c]
    } else if (tid < 160) {
        int c = tid - 128;
        float s = blz[c], s2 = blh[c];
        #pragma unroll
        for (int k = 0; k < 32; ++k) {
            s  += bz[k] * Wlz[k*32 + c];
            s2 += bh[k] * Wlh[k*32 + c];
        }
        cst[128 + c] = s;   // cz
        cst[288 + c] = s2;  // ch
    } else if (tid == 160) {
        float m = -1e30f;
        for (int t = 0; t < TD; ++t) m = fmaxf(m, attention[t]);
        float e[TD], s = 0.f;
        #pragma unroll
        for (int t = 0; t < TD; ++t) { e[t] = __expf(attention[t] - m); s += e[t]; }
        float inv = 1.f / s;
        #pragma unroll
        for (int t = 0; t < TD; ++t) cst[320 + t] = e[t] * inv;
    }
}

// deg[col] += w   (edge_index delivered as int32, layout [row[0..E-1], col[0..E-1]])
__global__ void deg_kernel(const int* __restrict__ ei, const float* __restrict__ w,
                           float* __restrict__ deg) {
    int e = blockIdx.x * blockDim.x + threadIdx.x;
    if (e < NE) {
        int col = ei[NE + e];
        atomicAdd(&deg[col], w[e]);
    }
}

__global__ void dis_kernel(const float* __restrict__ deg, float* __restrict__ dis) {
    int i = blockIdx.x * blockDim.x + threadIdx.x;
    if (i < NN) dis[i] = rsqrtf(deg[i] + 1.0f);
}

__global__ void norm_kernel(const int* __restrict__ ei, const float* __restrict__ w,
                            const float* __restrict__ dis, float* __restrict__ normv) {
    int e = blockIdx.x * blockDim.x + threadIdx.x;
    if (e < NE) {
        int r = ei[e];
        int c = ei[NE + e];
        normv[e] = dis[r] * w[e] * dis[c];
    }
}

// y[i,:] = dis[i]^2 * x[i,:]   (self-loop term), float4-vectorized
__global__ void init_y_kernel(const float4* __restrict__ x4, const float* __restrict__ dis,
                              float4* __restrict__ y4) {
    int j = blockIdx.x * blockDim.x + threadIdx.x;   // N*12 float4 chunks
    if (j < NN * (FT/4)) {
        int i = j / (FT/4);
        float d = dis[i]; d *= d;
        float4 v = x4[j];
        y4[j] = make_float4(v.x*d, v.y*d, v.z*d, v.w*d);
    }
}

// y[col,:] += norm[e] * x[row,:]  — one float4 chunk per work item (12 per edge)
__global__ void scatter_kernel(const int* __restrict__ ei, const float* __restrict__ normv,
                               const float4* __restrict__ x4, float* __restrict__ y) {
    int j = blockIdx.x * blockDim.x + threadIdx.x;   // NE*12 items < 2^31
    if (j >= NE * (FT/4)) return;
    int e  = j / (FT/4);
    int ch = j - e * (FT/4);
    float nv = normv[e];
    int r = ei[e];
    int c = ei[NE + e];
    float4 v = x4[r * (FT/4) + ch];
    float* dst = &y[c * FT + ch * 4];
    atomicAdd(dst + 0, nv * v.x);
    atomicAdd(dst + 1, nv * v.y);
    atomicAdd(dst + 2, nv * v.z);
    atomicAdd(dst + 3, nv * v.w);
}

// Per-node GRU (folded): for t: Z=sig(y_t@Az+cz), Ht=tanh(y_t@Ah+ch),
// Hacc += p[t]*(1-Z)*Ht ; out = relu(Hacc)@Wout + bout
// Block = 256 threads = 8 nodes x 32 channels.
__global__ __launch_bounds__(256) void gru_kernel(const float* __restrict__ y,
                                                  const float* __restrict__ cst,
                                                  const float* __restrict__ Wout,
                                                  const float* __restrict__ bout,
                                                  float* __restrict__ out) {
    __shared__ float sAz[128], sAh[128], sCz[32], sCh[32], sP[TD];
    __shared__ float sWout[CD * HD], sBout[HD];
    __shared__ float sy[8][FT];
    __shared__ float hbuf[8][CD];

    int tid = threadIdx.x;
    if (tid < 128) { sAz[tid] = cst[tid]; sAh[tid] = cst[160 + tid]; }
    if (tid < 32)  { sCz[tid] = cst[128 + tid]; sCh[tid] = cst[288 + tid]; }
    if (tid < TD)  { sP[tid] = cst[320 + tid]; sBout[tid] = bout[tid]; }
    for (int k = tid; k < CD * HD; k += 256) sWout[k] = Wout[k];

    int b0 = blockIdx.x * 8;   // first node of this block
    float* syf = &sy[0][0];
    for (int k = tid; k < 8 * FT; k += 256) {
        int idx = b0 * FT + k;
        syf[k] = (idx < NN * FT) ? y[idx] : 0.f;
    }
    __syncthreads();

    int ln = tid >> 5;        // local node 0..7
    int c  = tid & 31;        // channel

    float az0 = sAz[c], az1 = sAz[32 + c], az2 = sAz[64 + c], az3 = sAz[96 + c];
    float ah0 = sAh[c], ah1 = sAh[32 + c], ah2 = sAh[64 + c], ah3 = sAh[96 + c];
    float czc = sCz[c], chc = sCh[c];

    float hacc = 0.f;
    #pragma unroll
    for (int t = 0; t < TD; ++t) {
        float y0 = sy[ln][0*TD + t];
        float y1 = sy[ln][1*TD + t];
        float y2 = sy[ln][2*TD + t];
        float y3 = sy[ln][3*TD + t];
        float z = czc + y0*az0 + y1*az1 + y2*az2 + y3*az3;
        float h = chc + y0*ah0 + y1*ah1 + y2*ah2 + y3*ah3;
        float Z  = 1.f / (1.f + __expf(-z));
        float e2 = __expf(2.f * h);
        float Ht = (e2 - 1.f) / (e2 + 1.f);
        hacc += sP[t] * (1.f - Z) * Ht;
    }

    hbuf[ln][c] = fmaxf(hacc, 0.f);
    __syncthreads();

    if (tid < 8 * HD) {
        int lnode = tid / HD, hor = tid - lnode * HD;
        int gn = b0 + lnode;
        if (gn < NN) {
            float s = sBout[hor];
            #pragma unroll
            for (int k = 0; k < CD; ++k) s += hbuf[lnode][k] * sWout[k * HD + hor];
            out[gn * HD + hor] = s;
        }
    }
}

extern "C" void kernel_launch(void* const* d_in, const int* in_sizes, int n_in,
                              void* d_out, int out_size, void* d_ws, size_t ws_size,
                              hipStream_t stream) {
    const float* x      = (const float*)d_in[0];
    const int*   ei     = (const int*)d_in[1];    // int32, layout [rows..., cols...]
    const float* ew     = (const float*)d_in[2];
    const float* attn   = (const float*)d_in[3];
    const float* Wz     = (const float*)d_in[4];
    const float* bz     = (const float*)d_in[5];
    const float* Wlz    = (const float*)d_in[6];
    const float* blz    = (const float*)d_in[7];
    // d_in[8..11] = Wr, br, Wlr, blr  — dead (H0 == 0 forever)
    const float* Wh     = (const float*)d_in[12];
    const float* bh     = (const float*)d_in[13];
    const float* Wlh    = (const float*)d_in[14];
    const float* blh    = (const float*)d_in[15];
    const float* Wout   = (const float*)d_in[16];
    const float* bout   = (const float*)d_in[17];
    float* out = (float*)d_out;

    float* ws   = (float*)d_ws;
    float* deg  = ws + OFF_DEG;
    float* dis  = ws + OFF_DIS;
    float* nrm  = ws + OFF_NORM;
    float* y    = ws + OFF_Y;
    float* cst  = ws + OFF_CST;

    zero_deg_kernel<<<(NN + 255) / 256, 256, 0, stream>>>(deg);
    precompute_kernel<<<1, 256, 0, stream>>>(Wz, bz, Wlz, blz, Wh, bh, Wlh, blh, attn, cst);

    deg_kernel<<<(NE + 255) / 256, 256, 0, stream>>>(ei, ew, deg);
    dis_kernel<<<(NN + 255) / 256, 256, 0, stream>>>(deg, dis);
    norm_kernel<<<(NE + 255) / 256, 256, 0, stream>>>(ei, ew, dis, nrm);
    init_y_kernel<<<(NN * (FT/4) + 255) / 256, 256, 0, stream>>>((const float4*)x, dis, (float4*)y);
    scatter_kernel<<<(NE * (FT/4) + 255) / 256, 256, 0, stream>>>(ei, nrm, (const float4*)x, y);
    gru_kernel<<<(NN + 7) / 8, 256, 0, stream>>>(y, cst, Wout, bout, out);
}

// Round 3
// 288.978 us; speedup vs baseline: 2.3622x; 2.3622x over previous
//
#include <hip/hip_runtime.h>
#include <hip/hip_bf16.h>

// Problem constants
#define NN 50000      // nodes
#define NE 800000     // edges
#define FD 4          // features
#define TD 12         // timesteps
#define CD 32         // channels
#define HD 12         // horizon
#define FT 48         // FD*TD
#define NB 196        // ceil(NN/256) scan blocks

// Workspace layout (4-byte element offsets)
#define OFF_DEG    0                    // float[NN]
#define OFF_DIS    50000                // float[NN]
#define OFF_INDEG  100000               // int[NN]
#define OFF_OFF    150000               // int[NN]   CSR start offsets
#define OFF_FILL   200000               // int[NN]   bucket fill cursors
#define OFF_BSUM   250000               // int[256]
#define OFF_BOFF   250256               // int[256]
#define OFF_PAY    250512               // int2[NE]  (row, bitcast norm) — 8B aligned
#define OFF_Y      1850512              // float[NN*FT]
#define OFF_CST    4250512              // float[512]
// cst block: Az[128] @0, cz[32] @128, Ah[128] @160, ch[32] @288, probs[12] @320

__global__ void zero_kernel(float* __restrict__ deg, int* __restrict__ indeg) {
    int i = blockIdx.x * blockDim.x + threadIdx.x;
    if (i < NN) { deg[i] = 0.f; indeg[i] = 0; }
}

// ---------------------------------------------------------------------------
// Fused tiny matrices (H0 stays zero in the reference => R-gate dead, only the
// top 32 rows of Wlz/Wlh matter):
//   Az = Wz @ Wlz[0:32,:]  cz = blz + bz @ Wlz[0:32,:]   (same for h)
// ---------------------------------------------------------------------------
__global__ void precompute_kernel(const float* __restrict__ Wz, const float* __restrict__ bz,
                                  const float* __restrict__ Wlz, const float* __restrict__ blz,
                                  const float* __restrict__ Wh, const float* __restrict__ bh,
                                  const float* __restrict__ Wlh, const float* __restrict__ blh,
                                  const float* __restrict__ attention,
                                  float* __restrict__ cst) {
    int tid = threadIdx.x;
    if (tid < 128) {
        int f = tid >> 5, c = tid & 31;
        float s = 0.f, s2 = 0.f;
        #pragma unroll
        for (int k = 0; k < 32; ++k) {
            s  += Wz[f*32 + k] * Wlz[k*32 + c];
            s2 += Wh[f*32 + k] * Wlh[k*32 + c];
        }
        cst[tid]       = s;   // Az
        cst[160 + tid] = s2;  // Ah
    } else if (tid < 160) {
        int c = tid - 128;
        float s = blz[c], s2 = blh[c];
        #pragma unroll
        for (int k = 0; k < 32; ++k) {
            s  += bz[k] * Wlz[k*32 + c];
            s2 += bh[k] * Wlh[k*32 + c];
        }
        cst[128 + c] = s;   // cz
        cst[288 + c] = s2;  // ch
    } else if (tid == 160) {
        float m = -1e30f;
        for (int t = 0; t < TD; ++t) m = fmaxf(m, attention[t]);
        float e[TD], s = 0.f;
        #pragma unroll
        for (int t = 0; t < TD; ++t) { e[t] = __expf(attention[t] - m); s += e[t]; }
        float inv = 1.f / s;
        #pragma unroll
        for (int t = 0; t < TD; ++t) cst[320 + t] = e[t] * inv;
    }
}

// weighted degree + in-degree histogram (edge-parallel, int+float atomics)
__global__ void deg_hist_kernel(const int* __restrict__ ei, const float* __restrict__ w,
                                float* __restrict__ deg, int* __restrict__ indeg) {
    int e = blockIdx.x * blockDim.x + threadIdx.x;
    if (e < NE) {
        int c = ei[NE + e];
        atomicAdd(&deg[c], w[e]);
        atomicAdd(&indeg[c], 1);
    }
}

__global__ void dis_kernel(const float* __restrict__ deg, float* __restrict__ dis) {
    int i = blockIdx.x * blockDim.x + threadIdx.x;
    if (i < NN) dis[i] = rsqrtf(deg[i] + 1.0f);
}

// --- 3-step exclusive scan of indeg -> off -------------------------------
__global__ void scan1_kernel(const int* __restrict__ indeg, int* __restrict__ off,
                             int* __restrict__ bsum) {
    __shared__ int s[256];
    int t = threadIdx.x, i = blockIdx.x * 256 + t;
    int v = (i < NN) ? indeg[i] : 0;
    s[t] = v;
    __syncthreads();
    #pragma unroll
    for (int o = 1; o < 256; o <<= 1) {
        int tmp = (t >= o) ? s[t - o] : 0;
        __syncthreads();
        s[t] += tmp;
        __syncthreads();
    }
    if (i < NN) off[i] = s[t] - v;          // exclusive
    if (t == 255) bsum[blockIdx.x] = s[255]; // block total
}

__global__ void scan2_kernel(int* __restrict__ bsum, int* __restrict__ boff) {
    __shared__ int s[256];
    int t = threadIdx.x;
    int v = (t < NB) ? bsum[t] : 0;
    s[t] = v;
    __syncthreads();
    #pragma unroll
    for (int o = 1; o < 256; o <<= 1) {
        int tmp = (t >= o) ? s[t - o] : 0;
        __syncthreads();
        s[t] += tmp;
        __syncthreads();
    }
    boff[t] = s[t] - v;                      // exclusive
}

__global__ void scan3_kernel(int* __restrict__ off, const int* __restrict__ boff,
                             int* __restrict__ fill) {
    int i = blockIdx.x * blockDim.x + threadIdx.x;
    if (i < NN) {
        int o = off[i] + boff[i >> 8];
        off[i] = o;
        fill[i] = o;
    }
}

// bucket-fill CSR payload: (row, norm) per incoming edge of each node
__global__ void fill_kernel(const int* __restrict__ ei, const float* __restrict__ w,
                            const float* __restrict__ dis, int* __restrict__ fill,
                            int2* __restrict__ pay) {
    int e = blockIdx.x * blockDim.x + threadIdx.x;
    if (e < NE) {
        int r = ei[e];
        int c = ei[NE + e];
        float nv = dis[r] * w[e] * dis[c];
        int pos = atomicAdd(&fill[c], 1);
        pay[pos] = make_int2(r, __float_as_int(nv));
    }
}

// gather: thread = (node, float4-chunk); zero atomics.
// y[i,:] = dis[i]^2 * x[i,:] + sum_{incoming e} norm[e] * x[row[e],:]
__global__ __launch_bounds__(256) void gather_kernel(const float4* __restrict__ x4,
                                                     const float* __restrict__ dis,
                                                     const int* __restrict__ off,
                                                     const int* __restrict__ indeg,
                                                     const int2* __restrict__ pay,
                                                     float4* __restrict__ y4) {
    int j = blockIdx.x * blockDim.x + threadIdx.x;
    if (j >= NN * (FT/4)) return;
    int i  = j / (FT/4);
    int ch = j - i * (FT/4);
    float d = dis[i];
    float4 a = x4[i * (FT/4) + ch];
    float s0 = d * d;
    float4 acc = make_float4(a.x*s0, a.y*s0, a.z*s0, a.w*s0);
    int k0 = off[i], k1 = k0 + indeg[i];
    for (int k = k0; k < k1; ++k) {
        int2 p = pay[k];
        float nv = __int_as_float(p.y);
        float4 v = x4[p.x * (FT/4) + ch];
        acc.x += nv * v.x; acc.y += nv * v.y; acc.z += nv * v.z; acc.w += nv * v.w;
    }
    y4[j] = acc;
}

// Per-node folded GRU: Z=sig(y_t@Az+cz), Ht=tanh(y_t@Ah+ch),
// Hacc += p[t]*(1-Z)*Ht ; out = relu(Hacc)@Wout + bout
__global__ __launch_bounds__(256) void gru_kernel(const float* __restrict__ y,
                                                  const float* __restrict__ cst,
                                                  const float* __restrict__ Wout,
                                                  const float* __restrict__ bout,
                                                  float* __restrict__ out) {
    __shared__ float sAz[128], sAh[128], sCz[32], sCh[32], sP[TD];
    __shared__ float sWout[CD * HD], sBout[HD];
    __shared__ float sy[8][FT];
    __shared__ float hbuf[8][CD];

    int tid = threadIdx.x;
    if (tid < 128) { sAz[tid] = cst[tid]; sAh[tid] = cst[160 + tid]; }
    if (tid < 32)  { sCz[tid] = cst[128 + tid]; sCh[tid] = cst[288 + tid]; }
    if (tid < TD)  { sP[tid] = cst[320 + tid]; sBout[tid] = bout[tid]; }
    for (int k = tid; k < CD * HD; k += 256) sWout[k] = Wout[k];

    int b0 = blockIdx.x * 8;
    float* syf = &sy[0][0];
    for (int k = tid; k < 8 * FT; k += 256) {
        int idx = b0 * FT + k;
        syf[k] = (idx < NN * FT) ? y[idx] : 0.f;
    }
    __syncthreads();

    int ln = tid >> 5;
    int c  = tid & 31;

    float az0 = sAz[c], az1 = sAz[32 + c], az2 = sAz[64 + c], az3 = sAz[96 + c];
    float ah0 = sAh[c], ah1 = sAh[32 + c], ah2 = sAh[64 + c], ah3 = sAh[96 + c];
    float czc = sCz[c], chc = sCh[c];

    float hacc = 0.f;
    #pragma unroll
    for (int t = 0; t < TD; ++t) {
        float y0 = sy[ln][0*TD + t];
        float y1 = sy[ln][1*TD + t];
        float y2 = sy[ln][2*TD + t];
        float y3 = sy[ln][3*TD + t];
        float z = czc + y0*az0 + y1*az1 + y2*az2 + y3*az3;
        float h = chc + y0*ah0 + y1*ah1 + y2*ah2 + y3*ah3;
        float Z  = 1.f / (1.f + __expf(-z));
        float e2 = __expf(2.f * h);
        float Ht = (e2 - 1.f) / (e2 + 1.f);
        hacc += sP[t] * (1.f - Z) * Ht;
    }

    hbuf[ln][c] = fmaxf(hacc, 0.f);
    __syncthreads();

    if (tid < 8 * HD) {
        int lnode = tid / HD, hor = tid - lnode * HD;
        int gn = b0 + lnode;
        if (gn < NN) {
            float s = sBout[hor];
            #pragma unroll
            for (int k = 0; k < CD; ++k) s += hbuf[lnode][k] * sWout[k * HD + hor];
            out[gn * HD + hor] = s;
        }
    }
}

extern "C" void kernel_launch(void* const* d_in, const int* in_sizes, int n_in,
                              void* d_out, int out_size, void* d_ws, size_t ws_size,
                              hipStream_t stream) {
    const float* x      = (const float*)d_in[0];
    const int*   ei     = (const int*)d_in[1];    // int32, layout [rows..., cols...]
    const float* ew     = (const float*)d_in[2];
    const float* attn   = (const float*)d_in[3];
    const float* Wz     = (const float*)d_in[4];
    const float* bz     = (const float*)d_in[5];
    const float* Wlz    = (const float*)d_in[6];
    const float* blz    = (const float*)d_in[7];
    // d_in[8..11] = Wr, br, Wlr, blr — dead (H0 == 0 forever)
    const float* Wh     = (const float*)d_in[12];
    const float* bh     = (const float*)d_in[13];
    const float* Wlh    = (const float*)d_in[14];
    const float* blh    = (const float*)d_in[15];
    const float* Wout   = (const float*)d_in[16];
    const float* bout   = (const float*)d_in[17];
    float* out = (float*)d_out;

    float* ws    = (float*)d_ws;
    float* deg   = ws + OFF_DEG;
    float* dis   = ws + OFF_DIS;
    int*   indeg = (int*)(ws + OFF_INDEG);
    int*   off   = (int*)(ws + OFF_OFF);
    int*   fill  = (int*)(ws + OFF_FILL);
    int*   bsum  = (int*)(ws + OFF_BSUM);
    int*   boff  = (int*)(ws + OFF_BOFF);
    int2*  pay   = (int2*)(ws + OFF_PAY);
    float* y     = ws + OFF_Y;
    float* cst   = ws + OFF_CST;

    zero_kernel<<<NB, 256, 0, stream>>>(deg, indeg);
    precompute_kernel<<<1, 256, 0, stream>>>(Wz, bz, Wlz, blz, Wh, bh, Wlh, blh, attn, cst);

    deg_hist_kernel<<<(NE + 255) / 256, 256, 0, stream>>>(ei, ew, deg, indeg);
    dis_kernel<<<NB, 256, 0, stream>>>(deg, dis);

    scan1_kernel<<<NB, 256, 0, stream>>>(indeg, off, bsum);
    scan2_kernel<<<1, 256, 0, stream>>>(bsum, boff);
    scan3_kernel<<<NB, 256, 0, stream>>>(off, boff, fill);

    fill_kernel<<<(NE + 255) / 256, 256, 0, stream>>>(ei, ew, dis, fill, pay);

    gather_kernel<<<(NN * (FT/4) + 255) / 256, 256, 0, stream>>>(
        (const float4*)x, dis, off, indeg, pay, (float4*)y);

    gru_kernel<<<(NN + 7) / 8, 256, 0, stream>>>(y, cst, Wout, bout, out);
}

// Round 6
// 254.996 us; speedup vs baseline: 2.6770x; 1.1333x over previous
//
#include <hip/hip_runtime.h>
#include <hip/hip_bf16.h>

// Problem constants
#define NN 50000      // nodes
#define NE 800000     // edges
#define FD 4          // features
#define TD 12         // timesteps
#define CD 32         // channels
#define HD 12         // horizon
#define FT 48         // FD*TD
#define NB 196        // ceil(NN/256) scan blocks
#define NBANK 8       // histogram sub-banks (contention reduction)

// Workspace layout (4-byte element offsets)
#define OFF_CNT8   0                    // int[8*NN]  banked in-degree histogram
#define OFF_INDEG  400000               // int[NN]    total in-degree
#define OFF_OFF    450000               // int[NN]    CSR start offsets
#define OFF_SUB    500000               // int[8*NN]  banked fill cursors
#define OFF_BSUM   900000               // int[256]
#define OFF_BOFF   900256               // int[256]
#define OFF_DIS    900512               // float[NN]
#define OFF_PAY    950512               // int2[NE] (row, bitcast w) — 8B aligned
#define OFF_Y      2550512              // float[NN*FT]
#define OFF_CST    4950512              // float[512]
// cst block: Az[128] @0, cz[32] @128, Ah[128] @160, ch[32] @288, probs[12] @320

__global__ void zero_kernel(int* __restrict__ cnt8) {
    int i = blockIdx.x * blockDim.x + threadIdx.x;
    if (i < NBANK * NN) cnt8[i] = 0;
}

// ---------------------------------------------------------------------------
// Fused tiny matrices (H0 stays zero in the reference => R-gate dead, only the
// top 32 rows of Wlz/Wlh matter):
//   Az = Wz @ Wlz[0:32,:]  cz = blz + bz @ Wlz[0:32,:]   (same for h)
// ---------------------------------------------------------------------------
__global__ void precompute_kernel(const float* __restrict__ Wz, const float* __restrict__ bz,
                                  const float* __restrict__ Wlz, const float* __restrict__ blz,
                                  const float* __restrict__ Wh, const float* __restrict__ bh,
                                  const float* __restrict__ Wlh, const float* __restrict__ blh,
                                  const float* __restrict__ attention,
                                  float* __restrict__ cst) {
    int tid = threadIdx.x;
    if (tid < 128) {
        int f = tid >> 5, c = tid & 31;
        float s = 0.f, s2 = 0.f;
        #pragma unroll
        for (int k = 0; k < 32; ++k) {
            s  += Wz[f*32 + k] * Wlz[k*32 + c];
            s2 += Wh[f*32 + k] * Wlh[k*32 + c];
        }
        cst[tid]       = s;   // Az
        cst[160 + tid] = s2;  // Ah
    } else if (tid < 160) {
        int c = tid - 128;
        float s = blz[c], s2 = blh[c];
        #pragma unroll
        for (int k = 0; k < 32; ++k) {
            s  += bz[k] * Wlz[k*32 + c];
            s2 += bh[k] * Wlh[k*32 + c];
        }
        cst[128 + c] = s;   // cz
        cst[288 + c] = s2;  // ch
    } else if (tid == 160) {
        float m = -1e30f;
        for (int t = 0; t < TD; ++t) m = fmaxf(m, attention[t]);
        float e[TD], s = 0.f;
        #pragma unroll
        for (int t = 0; t < TD; ++t) { e[t] = __expf(attention[t] - m); s += e[t]; }
        float inv = 1.f / s;
        #pragma unroll
        for (int t = 0; t < TD; ++t) cst[320 + t] = e[t] * inv;
    }
}

// banked in-degree histogram: one int atomic per edge, 8x less contention
__global__ void hist_kernel(const int* __restrict__ ei, int* __restrict__ cnt8) {
    int e = blockIdx.x * blockDim.x + threadIdx.x;
    if (e < NE) {
        int c = ei[NE + e];
        atomicAdd(&cnt8[(e & (NBANK-1)) * NN + c], 1);
    }
}

// --- scan: per-node total, block-exclusive scan -----------------------------
__global__ void scan1_kernel(const int* __restrict__ cnt8, int* __restrict__ indeg,
                             int* __restrict__ off, int* __restrict__ bsum) {
    __shared__ int s[256];
    int t = threadIdx.x, i = blockIdx.x * 256 + t;
    int v = 0;
    if (i < NN) {
        #pragma unroll
        for (int b = 0; b < NBANK; ++b) v += cnt8[b * NN + i];
        indeg[i] = v;
    }
    s[t] = v;
    __syncthreads();
    #pragma unroll
    for (int o = 1; o < 256; o <<= 1) {
        int tmp = (t >= o) ? s[t - o] : 0;
        __syncthreads();
        s[t] += tmp;
        __syncthreads();
    }
    if (i < NN) off[i] = s[t] - v;          // exclusive within block
    if (t == 255) bsum[blockIdx.x] = s[255]; // block total
}

__global__ void scan2_kernel(int* __restrict__ bsum, int* __restrict__ boff) {
    __shared__ int s[256];
    int t = threadIdx.x;
    int v = (t < NB) ? bsum[t] : 0;
    s[t] = v;
    __syncthreads();
    #pragma unroll
    for (int o = 1; o < 256; o <<= 1) {
        int tmp = (t >= o) ? s[t - o] : 0;
        __syncthreads();
        s[t] += tmp;
        __syncthreads();
    }
    boff[t] = s[t] - v;                      // exclusive
}

// finalize global offsets + per-bank fill cursors
__global__ void scan3_kernel(int* __restrict__ off, const int* __restrict__ boff,
                             const int* __restrict__ cnt8, int* __restrict__ subfill) {
    int i = blockIdx.x * blockDim.x + threadIdx.x;
    if (i < NN) {
        int o = off[i] + boff[i >> 8];
        off[i] = o;
        int s = o;
        #pragma unroll
        for (int b = 0; b < NBANK; ++b) {
            subfill[b * NN + i] = s;
            s += cnt8[b * NN + i];
        }
    }
}

// bucket-fill CSR payload (row, raw weight); banked cursors (8x less contention)
__global__ void fill_kernel(const int* __restrict__ ei, const float* __restrict__ w,
                            int* __restrict__ subfill, int2* __restrict__ pay) {
    int e = blockIdx.x * blockDim.x + threadIdx.x;
    if (e < NE) {
        int r = ei[e];
        int c = ei[NE + e];
        int pos = atomicAdd(&subfill[(e & (NBANK-1)) * NN + c], 1);
        pay[pos] = make_int2(r, __float_as_int(w[e]));
    }
}

// weighted in-degree from the CSR bucket (contention-free) -> dis
__global__ void degdis_kernel(const int* __restrict__ off, const int* __restrict__ indeg,
                              const int2* __restrict__ pay, float* __restrict__ dis) {
    int i = blockIdx.x * blockDim.x + threadIdx.x;
    if (i < NN) {
        int k0 = off[i], k1 = k0 + indeg[i];
        float s = 0.f;
        for (int k = k0; k < k1; ++k) s += __int_as_float(pay[k].y);
        dis[i] = rsqrtf(s + 1.0f);
    }
}

// gather: thread = (node, float4-chunk); zero atomics.
// y[i,:] = dis[i]^2 * x[i,:] + dis[i] * sum_e dis[row]*w * x[row,:]
__global__ __launch_bounds__(256) void gather_kernel(const float4* __restrict__ x4,
                                                     const float* __restrict__ dis,
                                                     const int* __restrict__ off,
                                                     const int* __restrict__ indeg,
                                                     const int2* __restrict__ pay,
                                                     float4* __restrict__ y4) {
    int j = blockIdx.x * blockDim.x + threadIdx.x;
    if (j >= NN * (FT/4)) return;
    int i  = j / (FT/4);
    int ch = j - i * (FT/4);
    float d = dis[i];
    float4 a = x4[i * (FT/4) + ch];
    float4 acc = make_float4(0.f, 0.f, 0.f, 0.f);
    int k0 = off[i], k1 = k0 + indeg[i];
    for (int k = k0; k < k1; ++k) {
        int2 p = pay[k];
        float nv = dis[p.x] * __int_as_float(p.y);
        float4 v = x4[p.x * (FT/4) + ch];
        acc.x += nv * v.x; acc.y += nv * v.y; acc.z += nv * v.z; acc.w += nv * v.w;
    }
    float s0 = d * d;
    y4[j] = make_float4(a.x*s0 + d*acc.x, a.y*s0 + d*acc.y,
                        a.z*s0 + d*acc.z, a.w*s0 + d*acc.w);
}

// Per-node folded GRU: Z=sig(y_t@Az+cz), Ht=tanh(y_t@Ah+ch),
// Hacc += p[t]*(1-Z)*Ht ; out = relu(Hacc)@Wout + bout
__global__ __launch_bounds__(256) void gru_kernel(const float* __restrict__ y,
                                                  const float* __restrict__ cst,
                                                  const float* __restrict__ Wout,
                                                  const float* __restrict__ bout,
                                                  float* __restrict__ out) {
    __shared__ float sAz[128], sAh[128], sCz[32], sCh[32], sP[TD];
    __shared__ float sWout[CD * HD], sBout[HD];
    __shared__ float sy[8][FT];
    __shared__ float hbuf[8][CD];

    int tid = threadIdx.x;
    if (tid < 128) { sAz[tid] = cst[tid]; sAh[tid] = cst[160 + tid]; }
    if (tid < 32)  { sCz[tid] = cst[128 + tid]; sCh[tid] = cst[288 + tid]; }
    if (tid < TD)  { sP[tid] = cst[320 + tid]; sBout[tid] = bout[tid]; }
    for (int k = tid; k < CD * HD; k += 256) sWout[k] = Wout[k];

    int b0 = blockIdx.x * 8;
    float* syf = &sy[0][0];
    for (int k = tid; k < 8 * FT; k += 256) {
        int idx = b0 * FT + k;
        syf[k] = (idx < NN * FT) ? y[idx] : 0.f;
    }
    __syncthreads();

    int ln = tid >> 5;
    int c  = tid & 31;

    float az0 = sAz[c], az1 = sAz[32 + c], az2 = sAz[64 + c], az3 = sAz[96 + c];
    float ah0 = sAh[c], ah1 = sAh[32 + c], ah2 = sAh[64 + c], ah3 = sAh[96 + c];
    float czc = sCz[c], chc = sCh[c];

    float hacc = 0.f;
    #pragma unroll
    for (int t = 0; t < TD; ++t) {
        float y0 = sy[ln][0*TD + t];
        float y1 = sy[ln][1*TD + t];
        float y2 = sy[ln][2*TD + t];
        float y3 = sy[ln][3*TD + t];
        float z = czc + y0*az0 + y1*az1 + y2*az2 + y3*az3;
        float h = chc + y0*ah0 + y1*ah1 + y2*ah2 + y3*ah3;
        float Z  = 1.f / (1.f + __expf(-z));
        float e2 = __expf(2.f * h);
        float Ht = (e2 - 1.f) / (e2 + 1.f);
        hacc += sP[t] * (1.f - Z) * Ht;
    }

    hbuf[ln][c] = fmaxf(hacc, 0.f);
    __syncthreads();

    if (tid < 8 * HD) {
        int lnode = tid / HD, hor = tid - lnode * HD;
        int gn = b0 + lnode;
        if (gn < NN) {
            float s = sBout[hor];
            #pragma unroll
            for (int k = 0; k < CD; ++k) s += hbuf[lnode][k] * sWout[k * HD + hor];
            out[gn * HD + hor] = s;
        }
    }
}

extern "C" void kernel_launch(void* const* d_in, const int* in_sizes, int n_in,
                              void* d_out, int out_size, void* d_ws, size_t ws_size,
                              hipStream_t stream) {
    const float* x      = (const float*)d_in[0];
    const int*   ei     = (const int*)d_in[1];    // int32, layout [rows..., cols...]
    const float* ew     = (const float*)d_in[2];
    const float* attn   = (const float*)d_in[3];
    const float* Wz     = (const float*)d_in[4];
    const float* bz     = (const float*)d_in[5];
    const float* Wlz    = (const float*)d_in[6];
    const float* blz    = (const float*)d_in[7];
    // d_in[8..11] = Wr, br, Wlr, blr — dead (H0 == 0 forever)
    const float* Wh     = (const float*)d_in[12];
    const float* bh     = (const float*)d_in[13];
    const float* Wlh    = (const float*)d_in[14];
    const float* blh    = (const float*)d_in[15];
    const float* Wout   = (const float*)d_in[16];
    const float* bout   = (const float*)d_in[17];
    float* out = (float*)d_out;

    float* ws     = (float*)d_ws;
    int*   cnt8   = (int*)(ws + OFF_CNT8);
    int*   indeg  = (int*)(ws + OFF_INDEG);
    int*   off    = (int*)(ws + OFF_OFF);
    int*   subfil = (int*)(ws + OFF_SUB);
    int*   bsum   = (int*)(ws + OFF_BSUM);
    int*   boff   = (int*)(ws + OFF_BOFF);
    float* dis    = ws + OFF_DIS;
    int2*  pay    = (int2*)(ws + OFF_PAY);
    float* y      = ws + OFF_Y;
    float* cst    = ws + OFF_CST;

    zero_kernel<<<(NBANK * NN + 255) / 256, 256, 0, stream>>>(cnt8);
    precompute_kernel<<<1, 256, 0, stream>>>(Wz, bz, Wlz, blz, Wh, bh, Wlh, blh, attn, cst);

    hist_kernel<<<(NE + 255) / 256, 256, 0, stream>>>(ei, cnt8);

    scan1_kernel<<<NB, 256, 0, stream>>>(cnt8, indeg, off, bsum);
    scan2_kernel<<<1, 256, 0, stream>>>(bsum, boff);
    scan3_kernel<<<NB, 256, 0, stream>>>(off, boff, cnt8, subfil);

    fill_kernel<<<(NE + 255) / 256, 256, 0, stream>>>(ei, ew, subfil, pay);

    degdis_kernel<<<NB, 256, 0, stream>>>(off, indeg, pay, dis);

    gather_kernel<<<(NN * (FT/4) + 255) / 256, 256, 0, stream>>>(
        (const float4*)x, dis, off, indeg, pay, (float4*)y);

    gru_kernel<<<(NN + 7) / 8, 256, 0, stream>>>(y, cst, Wout, bout, out);
}